// Round 9
// baseline (1101.609 us; speedup 1.0000x reference)
//
#include <hip/hip_runtime.h>

#define B_ 128
#define T_ 1024
#define D_ 128
#define H_ 128

typedef short bf16x8 __attribute__((ext_vector_type(8)));
typedef float f32x4 __attribute__((ext_vector_type(4)));

// pack 2 f32 -> 2 bf16 (RNE) in one instruction (no builtin on gfx950)
__device__ inline unsigned cvt_pk_bf16(float lo, float hi) {
    unsigned r;
    asm("v_cvt_pk_bf16_f32 %0, %1, %2" : "=v"(r) : "v"(lo), "v"(hi));
    return r;
}

// tanh(x) = 1 - 2/(1+2^(x*2*log2(e))): mul, v_exp, add, rcp, fma
__device__ inline float fast_tanh(float x) {
    float e = __builtin_amdgcn_exp2f(x * 2.885390081777927f);
    float r = __builtin_amdgcn_rcpf(1.0f + e);
    return fmaf(-2.0f, r, 1.0f);
}

// ---------------------------------------------------------------------------
// Kernel 1: xu[rid = b*T + t][h] = x_row @ U + (bu + bw)  -> out (f32).
// (unchanged)
// ---------------------------------------------------------------------------
__global__ __launch_bounds__(256) void xu_kernel(
    const float* __restrict__ x, const float* __restrict__ U,
    const float* __restrict__ bu, const float* __restrict__ bw,
    float* __restrict__ out)
{
    __shared__ bf16x8 uf[2048];  // [nt(8)][kk(4)][lane(64)]: U[k][16nt+(l&15)]
    const int tid  = threadIdx.x;
    const int lane = tid & 63;
    const int wave = tid >> 6;
    const int q = lane >> 4, c = lane & 15;

    for (int s = tid; s < 2048; s += 256) {
        int l = s & 63, kk = (s >> 6) & 3, nt = s >> 8;
        int lq = l >> 4, lc = l & 15;
        int kbase = 32 * kk + 8 * lq;
        int col = 16 * nt + lc;
        float v[8];
#pragma unroll
        for (int j = 0; j < 8; ++j) v[j] = U[(kbase + j) * H_ + col];
        union { bf16x8 v8; unsigned u[4]; } f;
#pragma unroll
        for (int j = 0; j < 4; ++j) f.u[j] = cvt_pk_bf16(v[2 * j], v[2 * j + 1]);
        uf[s] = f.v8;
    }

    f32x4 bias4[8];
#pragma unroll
    for (int nt = 0; nt < 8; ++nt) {
        const int cb = 16 * nt + 4 * q;
        f32x4 a = *(const f32x4*)(bu + cb);
        f32x4 b = *(const f32x4*)(bw + cb);
#pragma unroll
        for (int r = 0; r < 4; ++r) bias4[nt][r] = a[r] + b[r];
    }

    __syncthreads();

    for (int it = 0; it < 4; ++it) {
        const int row0 = (blockIdx.x * 4 + it) * 64 + wave * 16;
        bf16x8 af[4];
#pragma unroll
        for (int kk = 0; kk < 4; ++kk) {
            const float* px = x + (size_t)(row0 + c) * D_ + 32 * kk + 8 * q;
            f32x4 a0 = *(const f32x4*)px;
            f32x4 a1 = *(const f32x4*)(px + 4);
            union { bf16x8 v8; unsigned u[4]; } f;
            f.u[0] = cvt_pk_bf16(a0[0], a0[1]);
            f.u[1] = cvt_pk_bf16(a0[2], a0[3]);
            f.u[2] = cvt_pk_bf16(a1[0], a1[1]);
            f.u[3] = cvt_pk_bf16(a1[2], a1[3]);
            af[kk] = f.v8;
        }
        float* po = out + (size_t)(row0 + c) * H_ + 4 * q;
#pragma unroll
        for (int nt = 0; nt < 8; ++nt) {
            f32x4 acc = bias4[nt];
#pragma unroll
            for (int kk = 0; kk < 4; ++kk)
                acc = __builtin_amdgcn_mfma_f32_16x16x32_bf16(
                    uf[(nt * 4 + kk) * 64 + lane], af[kk], acc, 0, 0, 0);
            *(f32x4*)(po + 16 * nt) = acc;
        }
    }
}

// ---------------------------------------------------------------------------
// Kernel 2: serial recurrence, REGISTER-RESIDENT. 8 blocks x 64 thr (1 wave
// per 16-row batch group). No LDS, no barriers.
//
// Key trick: W-columns are assigned to MFMA tiles by the permutation
//   wcol(nt, i) = 32*(nt>>1) + 4*(nt&1) + 8*(i>>2) + (i&3)
// so that lane (c,q)'s D output of tile pair (2kk, 2kk+1), after tanh and
// cvt_pk, IS the next step's B-fragment af[kk] = st[c][32kk+8q .. +7]
// (4 dwords: tile2kk.dw0, tile2kk.dw1, tile2kk+1.dw0, tile2kk+1.dw1).
// Every lane owns cols 32kk+8q..+7 of its row c for xu-read, st-write and
// state -> fully lane-private recurrence; the wave's registers carry st.
// st memory layout (bf16, first 256B of each out row) is UNCHANGED.
// ---------------------------------------------------------------------------
__device__ __forceinline__ void scan_step(
    const bf16x8 (&wf)[8][4],
    const bf16x8 (&afIn)[4], bf16x8 (&afOut)[4],
    const f32x4 (&cur)[8], f32x4 (&nxt)[8],
    bool pref, const float*& prow, char*& pst, int q)
{
    // prefetch next xu row (lane-private cols) into the other bank
    if (pref) {
#pragma unroll
        for (int ntp = 0; ntp < 4; ++ntp) {
            nxt[2 * ntp]     = *(const f32x4*)(prow + 32 * ntp + 8 * q);
            nxt[2 * ntp + 1] = *(const f32x4*)(prow + 32 * ntp + 8 * q + 4);
        }
        prow += H_;
    }

#pragma unroll
    for (int ntp = 0; ntp < 4; ++ntp) {
        f32x4 a0 = cur[2 * ntp];      // C-init = xu cols 32ntp+8q..+3
        f32x4 a1 = cur[2 * ntp + 1];  // C-init = xu cols 32ntp+8q+4..+7
#pragma unroll
        for (int kk = 0; kk < 4; ++kk) {
            a0 = __builtin_amdgcn_mfma_f32_16x16x32_bf16(wf[2 * ntp][kk],     afIn[kk], a0, 0, 0, 0);
            a1 = __builtin_amdgcn_mfma_f32_16x16x32_bf16(wf[2 * ntp + 1][kk], afIn[kk], a1, 0, 0, 0);
        }
        float s0 = fast_tanh(a0[0]);
        float s1 = fast_tanh(a0[1]);
        float s2 = fast_tanh(a0[2]);
        float s3 = fast_tanh(a0[3]);
        float s4 = fast_tanh(a1[0]);
        float s5 = fast_tanh(a1[1]);
        float s6 = fast_tanh(a1[2]);
        float s7 = fast_tanh(a1[3]);

        union { bf16x8 v8; unsigned u[4]; } f;
        f.u[0] = cvt_pk_bf16(s0, s1);  // cols 32ntp+8q+0,1
        f.u[1] = cvt_pk_bf16(s2, s3);  // +2,3
        f.u[2] = cvt_pk_bf16(s4, s5);  // +4,5
        f.u[3] = cvt_pk_bf16(s6, s7);  // +6,7
        afOut[ntp] = f.v8;             // = st_t[c][32ntp+8q..+7] B-frag

        // store st_t row (bf16, original col order), 16B per kk-chunk
        *(bf16x8*)(pst + 64 * ntp + 16 * q) = f.v8;
    }
    pst += H_ * 4;
}

__global__ __launch_bounds__(64, 1) void scan_kernel(
    const float* __restrict__ xu_in, float* __restrict__ st_out,
    const float* __restrict__ h0, const float* __restrict__ W)
{
    const int lane = threadIdx.x;
    const int q = lane >> 4, c = lane & 15;
    const int b0 = blockIdx.x * 16;

    // wf[nt][kk]: A[m=c][k=32kk+8q+j] = W[32kk+8q+j][wcol(nt, c)]
    bf16x8 wf[8][4];
#pragma unroll
    for (int nt = 0; nt < 8; ++nt) {
        const int wcol = 32 * (nt >> 1) + 4 * (nt & 1) + 8 * (c >> 2) + (c & 3);
#pragma unroll
        for (int kk = 0; kk < 4; ++kk) {
            const int kbase = 32 * kk + 8 * q;
            float v[8];
#pragma unroll
            for (int j = 0; j < 8; ++j) v[j] = W[(kbase + j) * H_ + wcol];
            union { bf16x8 v8; unsigned u[4]; } f;
#pragma unroll
            for (int j = 0; j < 4; ++j) f.u[j] = cvt_pk_bf16(v[2 * j], v[2 * j + 1]);
            wf[nt][kk] = f.v8;
        }
    }

    // af_{-1} from h0: st_{-1}[c][32kk+8q..+7]
    bf16x8 afA[4], afB[4];
#pragma unroll
    for (int kk = 0; kk < 4; ++kk) {
        const float* ph = h0 + (size_t)(b0 + c) * H_ + 32 * kk + 8 * q;
        f32x4 a0 = *(const f32x4*)ph;
        f32x4 a1 = *(const f32x4*)(ph + 4);
        union { bf16x8 v8; unsigned u[4]; } f;
        f.u[0] = cvt_pk_bf16(a0[0], a0[1]);
        f.u[1] = cvt_pk_bf16(a0[2], a0[3]);
        f.u[2] = cvt_pk_bf16(a1[0], a1[1]);
        f.u[3] = cvt_pk_bf16(a1[2], a1[3]);
        afA[kk] = f.v8;
    }

    // xu row 0 into bank A; prow then points at row 1
    const float* prow = xu_in + (size_t)(b0 + c) * T_ * H_;
    f32x4 curA[8], curB[8];
#pragma unroll
    for (int ntp = 0; ntp < 4; ++ntp) {
        curA[2 * ntp]     = *(const f32x4*)(prow + 32 * ntp + 8 * q);
        curA[2 * ntp + 1] = *(const f32x4*)(prow + 32 * ntp + 8 * q + 4);
    }
    prow += H_;

    char* pst = (char*)st_out + (size_t)(b0 + c) * T_ * H_ * 4;  // row t=0

    for (int t = 0; t < T_; t += 2) {
        scan_step(wf, afA, afB, curA, curB, true,       prow, pst, q);
        scan_step(wf, afB, afA, curB, curA, t + 2 < T_, prow, pst, q);
    }
}

// ---------------------------------------------------------------------------
// Kernel 3: o[row][h] = tanh(st_row @ V + bv), in-place over out. (unchanged)
// ---------------------------------------------------------------------------
__global__ __launch_bounds__(256) void o_kernel(
    const float* __restrict__ st_in, float* __restrict__ o_out,
    const float* __restrict__ V, const float* __restrict__ bv)
{
    __shared__ bf16x8 vf[2048];
    const int tid  = threadIdx.x;
    const int lane = tid & 63;
    const int wave = tid >> 6;
    const int q = lane >> 4, c = lane & 15;

    for (int s = tid; s < 2048; s += 256) {
        int l = s & 63, kk = (s >> 6) & 3, nt = s >> 8;
        int lq = l >> 4, lc = l & 15;
        int kbase = 32 * kk + 8 * lq;
        int col = 16 * nt + lc;
        float v[8];
#pragma unroll
        for (int j = 0; j < 8; ++j) v[j] = V[(kbase + j) * H_ + col];
        union { bf16x8 v8; unsigned u[4]; } f;
#pragma unroll
        for (int j = 0; j < 4; ++j) f.u[j] = cvt_pk_bf16(v[2 * j], v[2 * j + 1]);
        vf[s] = f.v8;
    }

    f32x4 bias4[8];
#pragma unroll
    for (int nt = 0; nt < 8; ++nt)
        bias4[nt] = *(const f32x4*)(bv + 16 * nt + 4 * q);

    __syncthreads();

    for (int it = 0; it < 4; ++it) {
        const int row0 = (blockIdx.x * 4 + it) * 64 + wave * 16;
        const char* pa = (const char*)st_in + (size_t)(row0 + c) * (H_ * 4);
        bf16x8 af[4];
#pragma unroll
        for (int kk = 0; kk < 4; ++kk)
            af[kk] = *(const bf16x8*)(pa + 64 * kk + 16 * q);
        float* po = o_out + (size_t)(row0 + c) * H_ + 4 * q;
#pragma unroll
        for (int nt = 0; nt < 8; ++nt) {
            f32x4 acc = bias4[nt];
#pragma unroll
            for (int kk = 0; kk < 4; ++kk)
                acc = __builtin_amdgcn_mfma_f32_16x16x32_bf16(
                    vf[(nt * 4 + kk) * 64 + lane], af[kk], acc, 0, 0, 0);
            f32x4 o;
#pragma unroll
            for (int r = 0; r < 4; ++r) o[r] = fast_tanh(acc[r]);
            *(f32x4*)(po + 16 * nt) = o;
        }
    }
}

extern "C" void kernel_launch(void* const* d_in, const int* in_sizes, int n_in,
                              void* d_out, int out_size, void* d_ws, size_t ws_size,
                              hipStream_t stream) {
    const float* x  = (const float*)d_in[0];
    const float* h0 = (const float*)d_in[1];
    const float* U  = (const float*)d_in[2];
    const float* W  = (const float*)d_in[3];
    const float* V  = (const float*)d_in[4];
    const float* bu = (const float*)d_in[5];
    const float* bw = (const float*)d_in[6];
    const float* bv = (const float*)d_in[7];
    float* out = (float*)d_out;

    // xu = x@U + (bu+bw) into out[B*T][H] (f32)
    xu_kernel<<<512, 256, 0, stream>>>(x, U, bu, bw, out);
    // serial recurrence: register-resident, 1 wave per 16-row group,
    // zero LDS / zero barriers (W-column permutation makes D-layout == B-frag)
    scan_kernel<<<8, 64, 0, stream>>>(out, out, h0, W);
    // o = tanh(st@V + bv), in-place over out (alias-split)
    o_kernel<<<512, 256, 0, stream>>>(out, out, V, bv);
}

// Round 10
// 825.338 us; speedup vs baseline: 1.3347x; 1.3347x over previous
//
#include <hip/hip_runtime.h>

#define B_ 128
#define T_ 1024
#define D_ 128
#define H_ 128

typedef short bf16x8 __attribute__((ext_vector_type(8)));
typedef float f32x4 __attribute__((ext_vector_type(4)));

// pack 2 f32 -> 2 bf16 (RNE) in one instruction (no builtin on gfx950)
__device__ inline unsigned cvt_pk_bf16(float lo, float hi) {
    unsigned r;
    asm("v_cvt_pk_bf16_f32 %0, %1, %2" : "=v"(r) : "v"(lo), "v"(hi));
    return r;
}

// tanh(x) = 1 - 2/(1+2^(x*2*log2(e))): mul, v_exp, add, rcp, fma
__device__ inline float fast_tanh(float x) {
    float e = __builtin_amdgcn_exp2f(x * 2.885390081777927f);
    float r = __builtin_amdgcn_rcpf(1.0f + e);
    return fmaf(-2.0f, r, 1.0f);
}

// lgkm-only barrier: keeps in-flight global loads/stores off the critical path
__device__ inline void lds_barrier() {
    asm volatile("s_waitcnt lgkmcnt(0)\n\ts_barrier" ::: "memory");
}

// ---------------------------------------------------------------------------
// Kernel 1: xu[rid = b*T + t][h] = x_row @ U + (bu + bw)  -> out (f32).
// (unchanged)
// ---------------------------------------------------------------------------
__global__ __launch_bounds__(256) void xu_kernel(
    const float* __restrict__ x, const float* __restrict__ U,
    const float* __restrict__ bu, const float* __restrict__ bw,
    float* __restrict__ out)
{
    __shared__ bf16x8 uf[2048];  // [nt(8)][kk(4)][lane(64)]: U[k][16nt+(l&15)]
    const int tid  = threadIdx.x;
    const int lane = tid & 63;
    const int wave = tid >> 6;
    const int q = lane >> 4, c = lane & 15;

    for (int s = tid; s < 2048; s += 256) {
        int l = s & 63, kk = (s >> 6) & 3, nt = s >> 8;
        int lq = l >> 4, lc = l & 15;
        int kbase = 32 * kk + 8 * lq;
        int col = 16 * nt + lc;
        float v[8];
#pragma unroll
        for (int j = 0; j < 8; ++j) v[j] = U[(kbase + j) * H_ + col];
        union { bf16x8 v8; unsigned u[4]; } f;
#pragma unroll
        for (int j = 0; j < 4; ++j) f.u[j] = cvt_pk_bf16(v[2 * j], v[2 * j + 1]);
        uf[s] = f.v8;
    }

    f32x4 bias4[8];
#pragma unroll
    for (int nt = 0; nt < 8; ++nt) {
        const int cb = 16 * nt + 4 * q;
        f32x4 a = *(const f32x4*)(bu + cb);
        f32x4 b = *(const f32x4*)(bw + cb);
#pragma unroll
        for (int r = 0; r < 4; ++r) bias4[nt][r] = a[r] + b[r];
    }

    __syncthreads();

    for (int it = 0; it < 4; ++it) {
        const int row0 = (blockIdx.x * 4 + it) * 64 + wave * 16;
        bf16x8 af[4];
#pragma unroll
        for (int kk = 0; kk < 4; ++kk) {
            const float* px = x + (size_t)(row0 + c) * D_ + 32 * kk + 8 * q;
            f32x4 a0 = *(const f32x4*)px;
            f32x4 a1 = *(const f32x4*)(px + 4);
            union { bf16x8 v8; unsigned u[4]; } f;
            f.u[0] = cvt_pk_bf16(a0[0], a0[1]);
            f.u[1] = cvt_pk_bf16(a0[2], a0[3]);
            f.u[2] = cvt_pk_bf16(a1[0], a1[1]);
            f.u[3] = cvt_pk_bf16(a1[2], a1[3]);
            af[kk] = f.v8;
        }
        float* po = out + (size_t)(row0 + c) * H_ + 4 * q;
#pragma unroll
        for (int nt = 0; nt < 8; ++nt) {
            f32x4 acc = bias4[nt];
#pragma unroll
            for (int kk = 0; kk < 4; ++kk)
                acc = __builtin_amdgcn_mfma_f32_16x16x32_bf16(
                    uf[(nt * 4 + kk) * 64 + lane], af[kk], acc, 0, 0, 0);
            *(f32x4*)(po + 16 * nt) = acc;
        }
    }
}

// ---------------------------------------------------------------------------
// Kernel 2: serial recurrence, 8 blocks x 128 thr (2 waves per 16-row group).
// R9's verified W-column permutation (wcol(nt,i) = 32(nt>>1)+4(nt&1)+8(i>>2)
// +(i&3)) makes lane (c,q)'s packed D output of tile pair kk IDENTICAL to
// next step's B-frag af[kk] = st[c][32kk+8q..+7]. Wave w owns tile pairs
// {2w, 2w+1} -> wf is only 64 VGPRs/wave (R9's 1-wave version demanded ~240
// VGPRs, got 152 allocated -> spill/remat stall of ~1800cy/step). The two
// waves exchange their half of the af frags through a double-buffered LDS
// slot; one lgkm barrier per step.
// ---------------------------------------------------------------------------
__device__ __forceinline__ void scan_step2(
    int t, int par, const bf16x8 (&wf)[4][4],
    const f32x4 (&cur)[4], f32x4 (&nxt)[4],
    const float*& prow, char*& pst,
    short (&xf)[2][4][64][8], int lane, int w)
{
    // 1) read full st_{t-1} frags from slot[par^1]
    bf16x8 af[4];
#pragma unroll
    for (int kk = 0; kk < 4; ++kk)
        af[kk] = *(const bf16x8*)&xf[par ^ 1][kk][lane][0];

    // 2) prefetch this wave's xu cols of row t+1
    if (t + 1 < T_) {
#pragma unroll
        for (int pl = 0; pl < 2; ++pl) {
            nxt[2 * pl]     = *(const f32x4*)(prow + 32 * pl);
            nxt[2 * pl + 1] = *(const f32x4*)(prow + 32 * pl + 4);
        }
        prow += H_;
    }

    const f32x4 z4 = {0.f, 0.f, 0.f, 0.f};

    // 3) per local tile pair: depth-2 MFMA chains, tanh, pack, store, exchange
#pragma unroll
    for (int pl = 0; pl < 2; ++pl) {
        f32x4 aA = __builtin_amdgcn_mfma_f32_16x16x32_bf16(wf[2 * pl][0],     af[0], cur[2 * pl],     0, 0, 0);
        f32x4 aB = __builtin_amdgcn_mfma_f32_16x16x32_bf16(wf[2 * pl][1],     af[1], z4,              0, 0, 0);
        f32x4 bA = __builtin_amdgcn_mfma_f32_16x16x32_bf16(wf[2 * pl + 1][0], af[0], cur[2 * pl + 1], 0, 0, 0);
        f32x4 bB = __builtin_amdgcn_mfma_f32_16x16x32_bf16(wf[2 * pl + 1][1], af[1], z4,              0, 0, 0);
        aA = __builtin_amdgcn_mfma_f32_16x16x32_bf16(wf[2 * pl][2],     af[2], aA, 0, 0, 0);
        aB = __builtin_amdgcn_mfma_f32_16x16x32_bf16(wf[2 * pl][3],     af[3], aB, 0, 0, 0);
        bA = __builtin_amdgcn_mfma_f32_16x16x32_bf16(wf[2 * pl + 1][2], af[2], bA, 0, 0, 0);
        bB = __builtin_amdgcn_mfma_f32_16x16x32_bf16(wf[2 * pl + 1][3], af[3], bB, 0, 0, 0);

        float s0 = fast_tanh(aA[0] + aB[0]);
        float s1 = fast_tanh(aA[1] + aB[1]);
        float s2 = fast_tanh(aA[2] + aB[2]);
        float s3 = fast_tanh(aA[3] + aB[3]);
        float s4 = fast_tanh(bA[0] + bB[0]);
        float s5 = fast_tanh(bA[1] + bB[1]);
        float s6 = fast_tanh(bA[2] + bB[2]);
        float s7 = fast_tanh(bA[3] + bB[3]);

        union { bf16x8 v8; unsigned u[4]; } f;
        f.u[0] = cvt_pk_bf16(s0, s1);  // cols 32kk+8q+0,1  (kk = 2w+pl)
        f.u[1] = cvt_pk_bf16(s2, s3);  // +2,3
        f.u[2] = cvt_pk_bf16(s4, s5);  // +4,5
        f.u[3] = cvt_pk_bf16(s6, s7);  // +6,7

        *(bf16x8*)(pst + 64 * pl) = f.v8;                 // global st row t
        *(bf16x8*)&xf[par][2 * w + pl][lane][0] = f.v8;   // LDS exchange
    }
    pst += 512;

    // 4) ds_writes visible to the other wave
    lds_barrier();
}

__global__ __launch_bounds__(128, 1) void scan_kernel(
    const float* __restrict__ xu_in, float* __restrict__ st_out,
    const float* __restrict__ h0, const float* __restrict__ W)
{
    __shared__ __align__(16) short xf[2][4][64][8];  // [par][kk][lane][bf16x8]

    const int tid  = threadIdx.x;
    const int lane = tid & 63;
    const int w    = tid >> 6;           // wave 0,1
    const int q = lane >> 4, c = lane & 15;
    const int b0 = blockIdx.x * 16;

    // wf[ntl][kk]: A-frag of W for tile nt = 4w+ntl (pairs 2w, 2w+1)
    bf16x8 wf[4][4];
#pragma unroll
    for (int ntl = 0; ntl < 4; ++ntl) {
        const int nt = 4 * w + ntl;
        const int wcol = 32 * (nt >> 1) + 4 * (nt & 1) + 8 * (c >> 2) + (c & 3);
#pragma unroll
        for (int kk = 0; kk < 4; ++kk) {
            const int kbase = 32 * kk + 8 * q;
            float v[8];
#pragma unroll
            for (int j = 0; j < 8; ++j) v[j] = W[(kbase + j) * H_ + wcol];
            union { bf16x8 v8; unsigned u[4]; } f;
#pragma unroll
            for (int j = 0; j < 4; ++j) f.u[j] = cvt_pk_bf16(v[2 * j], v[2 * j + 1]);
            wf[ntl][kk] = f.v8;
        }
    }

    // h0 -> own frags (kk = 2w, 2w+1) -> slot[1] (read by step t=0)
#pragma unroll
    for (int j = 0; j < 2; ++j) {
        const int kk = 2 * w + j;
        const float* ph = h0 + (size_t)(b0 + c) * H_ + 32 * kk + 8 * q;
        f32x4 a0 = *(const f32x4*)ph;
        f32x4 a1 = *(const f32x4*)(ph + 4);
        union { bf16x8 v8; unsigned u[4]; } f;
        f.u[0] = cvt_pk_bf16(a0[0], a0[1]);
        f.u[1] = cvt_pk_bf16(a0[2], a0[3]);
        f.u[2] = cvt_pk_bf16(a1[0], a1[1]);
        f.u[3] = cvt_pk_bf16(a1[2], a1[3]);
        *(bf16x8*)&xf[1][kk][lane][0] = f.v8;
    }

    // xu row 0 -> curA; this wave's cols: 64w + 32pl + 8q (+4)
    const float* prow = xu_in + (size_t)(b0 + c) * T_ * H_ + 64 * w + 8 * q;
    f32x4 curA[4], curB[4];
#pragma unroll
    for (int pl = 0; pl < 2; ++pl) {
        curA[2 * pl]     = *(const f32x4*)(prow + 32 * pl);
        curA[2 * pl + 1] = *(const f32x4*)(prow + 32 * pl + 4);
    }
    prow += H_;

    // st store base: row t, byte offset 128w + 16q (+64 for pl=1)
    char* pst = (char*)st_out + (size_t)(b0 + c) * T_ * H_ * 4 + 128 * w + 16 * q;

    lds_barrier();

    for (int t = 0; t < T_; t += 2) {
        scan_step2(t,     0, wf, curA, curB, prow, pst, xf, lane, w);
        scan_step2(t + 1, 1, wf, curB, curA, prow, pst, xf, lane, w);
    }
}

// ---------------------------------------------------------------------------
// Kernel 3: o[row][h] = tanh(st_row @ V + bv), in-place over out. (unchanged)
// ---------------------------------------------------------------------------
__global__ __launch_bounds__(256) void o_kernel(
    const float* __restrict__ st_in, float* __restrict__ o_out,
    const float* __restrict__ V, const float* __restrict__ bv)
{
    __shared__ bf16x8 vf[2048];
    const int tid  = threadIdx.x;
    const int lane = tid & 63;
    const int wave = tid >> 6;
    const int q = lane >> 4, c = lane & 15;

    for (int s = tid; s < 2048; s += 256) {
        int l = s & 63, kk = (s >> 6) & 3, nt = s >> 8;
        int lq = l >> 4, lc = l & 15;
        int kbase = 32 * kk + 8 * lq;
        int col = 16 * nt + lc;
        float v[8];
#pragma unroll
        for (int j = 0; j < 8; ++j) v[j] = V[(kbase + j) * H_ + col];
        union { bf16x8 v8; unsigned u[4]; } f;
#pragma unroll
        for (int j = 0; j < 4; ++j) f.u[j] = cvt_pk_bf16(v[2 * j], v[2 * j + 1]);
        vf[s] = f.v8;
    }

    f32x4 bias4[8];
#pragma unroll
    for (int nt = 0; nt < 8; ++nt)
        bias4[nt] = *(const f32x4*)(bv + 16 * nt + 4 * q);

    __syncthreads();

    for (int it = 0; it < 4; ++it) {
        const int row0 = (blockIdx.x * 4 + it) * 64 + wave * 16;
        const char* pa = (const char*)st_in + (size_t)(row0 + c) * (H_ * 4);
        bf16x8 af[4];
#pragma unroll
        for (int kk = 0; kk < 4; ++kk)
            af[kk] = *(const bf16x8*)(pa + 64 * kk + 16 * q);
        float* po = o_out + (size_t)(row0 + c) * H_ + 4 * q;
#pragma unroll
        for (int nt = 0; nt < 8; ++nt) {
            f32x4 acc = bias4[nt];
#pragma unroll
            for (int kk = 0; kk < 4; ++kk)
                acc = __builtin_amdgcn_mfma_f32_16x16x32_bf16(
                    vf[(nt * 4 + kk) * 64 + lane], af[kk], acc, 0, 0, 0);
            f32x4 o;
#pragma unroll
            for (int r = 0; r < 4; ++r) o[r] = fast_tanh(acc[r]);
            *(f32x4*)(po + 16 * nt) = o;
        }
    }
}

extern "C" void kernel_launch(void* const* d_in, const int* in_sizes, int n_in,
                              void* d_out, int out_size, void* d_ws, size_t ws_size,
                              hipStream_t stream) {
    const float* x  = (const float*)d_in[0];
    const float* h0 = (const float*)d_in[1];
    const float* U  = (const float*)d_in[2];
    const float* W  = (const float*)d_in[3];
    const float* V  = (const float*)d_in[4];
    const float* bu = (const float*)d_in[5];
    const float* bw = (const float*)d_in[6];
    const float* bv = (const float*)d_in[7];
    float* out = (float*)d_out;

    // xu = x@U + (bu+bw) into out[B*T][H] (f32)
    xu_kernel<<<512, 256, 0, stream>>>(x, U, bu, bw, out);
    // serial recurrence: 2 waves per 16-row group, permuted-layout register
    // recurrence + LDS half-frag exchange (no spill: ~170 VGPR demand/wave)
    scan_kernel<<<8, 128, 0, stream>>>(out, out, h0, W);
    // o = tanh(st@V + bv), in-place over out (alias-split)
    o_kernel<<<512, 256, 0, stream>>>(out, out, V, bv);
}